// Round 9
// baseline (316.831 us; speedup 1.0000x reference)
//
#include <hip/hip_runtime.h>

typedef _Float16 f16;
typedef _Float16 f16x4 __attribute__((ext_vector_type(4)));
typedef _Float16 f16x8 __attribute__((ext_vector_type(8)));
typedef float f32x4 __attribute__((ext_vector_type(4)));
typedef int i32x4 __attribute__((ext_vector_type(4)));

#define ALPHA 0.2f
#define NN 8192
#define DD 256
#define INVLN2 1.44269504088896f
#define MFMA16(a, b, c) __builtin_amdgcn_mfma_f32_16x16x32_f16(a, b, c, 0, 0, 0)

// ---------------- K0: prep — WT=f16(W^T), r1=W@a1*invln2, r2=W@a2*invln2 ----------
__global__ __launch_bounds__(256) void k0_prep(const float* __restrict__ W,
                                               const float* __restrict__ a,
                                               f16* __restrict__ WT,
                                               float* __restrict__ r1,
                                               float* __restrict__ r2) {
    const int b = blockIdx.x;
    const int t = threadIdx.x;
    if (b < 16) {
        __shared__ f16 tl[16][256];
        const int k0 = b * 16;
        const int kr = t >> 4, cb = (t & 15) << 4;
        #pragma unroll
        for (int p = 0; p < 4; ++p) {
            float4 v = *(const float4*)&W[(k0 + kr) * DD + cb + p * 4];
            tl[kr][cb + p * 4 + 0] = (f16)v.x;
            tl[kr][cb + p * 4 + 1] = (f16)v.y;
            tl[kr][cb + p * 4 + 2] = (f16)v.z;
            tl[kr][cb + p * 4 + 3] = (f16)v.w;
        }
        __syncthreads();
        f16 outv[16];
        #pragma unroll
        for (int q = 0; q < 16; ++q) outv[q] = tl[q][t];
        *(f16x8*)&WT[t * DD + k0]     = *(f16x8*)&outv[0];
        *(f16x8*)&WT[t * DD + k0 + 8] = *(f16x8*)&outv[8];
    } else {
        __shared__ float al[256];
        al[t] = a[(b - 16) * DD + t];
        __syncthreads();
        float s = 0.f;
        for (int k = 0; k < DD; ++k) s = fmaf(W[t * DD + k], al[k], s);
        float* rr = (b == 16) ? r1 : r2;
        rr[t] = s * INVLN2;
    }
}

// ---------------- K1: WhT = f16(h@W)^T via MFMA; wave0 also Wh1/Wh2 + maxkey ------
__global__ __launch_bounds__(256) void k1_gemm(const float* __restrict__ h,
                                               const f16* __restrict__ WT,
                                               const float* __restrict__ r1,
                                               const float* __restrict__ r2,
                                               f16* __restrict__ WhT,
                                               float* __restrict__ Wh1,
                                               float* __restrict__ Wh2,
                                               unsigned* __restrict__ maxkey) {
    const int t    = threadIdx.x;
    const int lane = t & 63;
    const int w    = t >> 6;
    const int i0   = blockIdx.x * 16;
    const int r    = lane & 15;
    const int hi   = lane >> 4;
    const int nbase = w * 64;

    f32x4 acc[4];
    #pragma unroll
    for (int nc = 0; nc < 4; ++nc) acc[nc] = (f32x4){0.f, 0.f, 0.f, 0.f};
    float s1 = 0.f, s2 = 0.f;

    const float* hrow = h + (size_t)(i0 + r) * DD;
    #pragma unroll
    for (int kt = 0; kt < 8; ++kt) {
        const int kb = kt * 32 + hi * 8;
        float4 h0 = *(const float4*)&hrow[kb];
        float4 h1 = *(const float4*)&hrow[kb + 4];
        f16x8 af;
        af[0] = (f16)h0.x; af[1] = (f16)h0.y; af[2] = (f16)h0.z; af[3] = (f16)h0.w;
        af[4] = (f16)h1.x; af[5] = (f16)h1.y; af[6] = (f16)h1.z; af[7] = (f16)h1.w;
        if (w == 0) {
            float4 ra0 = *(const float4*)&r1[kb];
            float4 ra1 = *(const float4*)&r1[kb + 4];
            float4 rb0 = *(const float4*)&r2[kb];
            float4 rb1 = *(const float4*)&r2[kb + 4];
            s1 += h0.x * ra0.x + h0.y * ra0.y + h0.z * ra0.z + h0.w * ra0.w
                + h1.x * ra1.x + h1.y * ra1.y + h1.z * ra1.z + h1.w * ra1.w;
            s2 += h0.x * rb0.x + h0.y * rb0.y + h0.z * rb0.z + h0.w * rb0.w
                + h1.x * rb1.x + h1.y * rb1.y + h1.z * rb1.z + h1.w * rb1.w;
        }
        #pragma unroll
        for (int nc = 0; nc < 4; ++nc) {
            f16x8 bf = *(const f16x8*)&WT[(nbase + nc * 16 + r) * DD + kb];
            acc[nc] = MFMA16(af, bf, acc[nc]);
        }
    }
    #pragma unroll
    for (int nc = 0; nc < 4; ++nc) {
        f16x4 o;
        o[0] = (f16)acc[nc][0]; o[1] = (f16)acc[nc][1];
        o[2] = (f16)acc[nc][2]; o[3] = (f16)acc[nc][3];
        *(f16x4*)&WhT[(size_t)(nbase + nc * 16 + r) * NN + i0 + hi * 4] = o;
    }
    if (w == 0) {
        s1 += __shfl_xor(s1, 16); s1 += __shfl_xor(s1, 32);
        s2 += __shfl_xor(s2, 16); s2 += __shfl_xor(s2, 32);
        if (lane < 16) {
            Wh1[i0 + lane] = s1;
            Wh2[i0 + lane] = s2;
            unsigned u = __float_as_uint(s2);
            u = (u & 0x80000000u) ? ~u : (u | 0x80000000u);
            atomicMax(maxkey, u);
        }
    }
}

// ---------------- K3: fused masked softmax + PV, in-register P ----------------
// grid = (NN/64)*js_n blocks x 512 thr (8 waves, 2iw x 4nw). Block: 64 i-rows,
// full n=256, j-steps of 64. WhT tile [256][64] dbuf in XOR-swizzled LDS (64KB).
// P built in-register per wave as MFMA B-operand (r2 mapping: lane&15=i, hi*8+e=j).
// adj queued one full step ahead in registers. 1 barrier/step. Partial D -> slab.
__device__ __forceinline__ f16x8 pcomp8(i32x4 a0, i32x4 a1, float4 q0, float4 q1,
                                        float wh1r, float m_r, float& sacc) {
    float p[8];
    float e;
    e = wh1r + q0.x; e = fmaxf(e, ALPHA * e); p[0] = (a0.x > 0) ? exp2f(e - m_r) : 0.f;
    e = wh1r + q0.y; e = fmaxf(e, ALPHA * e); p[1] = (a0.y > 0) ? exp2f(e - m_r) : 0.f;
    e = wh1r + q0.z; e = fmaxf(e, ALPHA * e); p[2] = (a0.z > 0) ? exp2f(e - m_r) : 0.f;
    e = wh1r + q0.w; e = fmaxf(e, ALPHA * e); p[3] = (a0.w > 0) ? exp2f(e - m_r) : 0.f;
    e = wh1r + q1.x; e = fmaxf(e, ALPHA * e); p[4] = (a1.x > 0) ? exp2f(e - m_r) : 0.f;
    e = wh1r + q1.y; e = fmaxf(e, ALPHA * e); p[5] = (a1.y > 0) ? exp2f(e - m_r) : 0.f;
    e = wh1r + q1.z; e = fmaxf(e, ALPHA * e); p[6] = (a1.z > 0) ? exp2f(e - m_r) : 0.f;
    e = wh1r + q1.w; e = fmaxf(e, ALPHA * e); p[7] = (a1.w > 0) ? exp2f(e - m_r) : 0.f;
    sacc += ((p[0] + p[1]) + (p[2] + p[3])) + ((p[4] + p[5]) + (p[6] + p[7]));
    f16x8 pk;
    pk[0] = (f16)p[0]; pk[1] = (f16)p[1]; pk[2] = (f16)p[2]; pk[3] = (f16)p[3];
    pk[4] = (f16)p[4]; pk[5] = (f16)p[5]; pk[6] = (f16)p[6]; pk[7] = (f16)p[7];
    return pk;
}

__global__ __launch_bounds__(512, 2) void k3_attn(const int* __restrict__ adj,
                                                  const f16* __restrict__ WhT,
                                                  const float* __restrict__ Wh1,
                                                  const float* __restrict__ Wh2,
                                                  const unsigned* __restrict__ maxkey,
                                                  float* __restrict__ D,
                                                  float* __restrict__ S,
                                                  int jrange, int jsmask, int jshift) {
    __shared__ __align__(16) f16 wbuf[2][256 * 64];   // 2 x 32 KB

    const int t     = threadIdx.x;
    const int lane  = t & 63;
    const int w     = t >> 6;
    const int js    = blockIdx.x & jsmask;
    const int itile = blockIdx.x >> jshift;
    const int i0    = itile * 64;
    const int jb0   = js * jrange;
    const int ns    = jrange >> 6;

    unsigned mk = *maxkey;
    const float maxW2 = __uint_as_float((mk & 0x80000000u) ? (mk & 0x7fffffffu) : ~mk);

    // roles
    const int r   = lane & 15;
    const int hi  = lane >> 4;
    const int hi8 = hi << 3;
    const int iw  = w >> 2;              // 0..1 : i-half
    const int nw  = w & 3;               // 0..3 : n-quarter
    const int nb  = nw * 64;
    const int rx  = (r & 7) << 4;        // A-read XOR swizzle
    // staging role
    const int sn  = t >> 3;              // 0..63
    const int jc  = t & 7;               // 16B slot
    const int swz = ((jc ^ (sn & 7)) << 4);

    // per-thread softmax row constants (2 i-rows: ic=0,1)
    const int ia = i0 + iw * 32 + r;
    const float wh10 = Wh1[ia];
    const float wh11 = Wh1[ia + 16];
    float t0 = wh10 + maxW2, t1 = wh11 + maxW2;
    const float m0 = fmaxf(t0, ALPHA * t0);
    const float m1 = fmaxf(t1, ALPHA * t1);
    const int* aRow0 = adj + (size_t)ia * NN;
    const int* aRow1 = adj + (size_t)(ia + 16) * NN;

    f32x4 acc[2][4];
    #pragma unroll
    for (int ic = 0; ic < 2; ++ic)
        #pragma unroll
        for (int nc = 0; nc < 4; ++nc) acc[ic][nc] = (f32x4){0.f, 0.f, 0.f, 0.f};
    float s0 = 0.f, s1 = 0.f;

    // ---- prologue: stage WhT step0, fill adj queue for step0 ----
    #pragma unroll
    for (int p = 0; p < 4; ++p) {
        const int rowp = p * 64 + sn;
        i32x4 wv = *(const i32x4*)(WhT + (size_t)rowp * NN + jb0 + jc * 8);
        *(i32x4*)((char*)wbuf[0] + rowp * 128 + swz) = wv;
    }
    i32x4 A00a = *(const i32x4*)(aRow0 + jb0 + hi8);
    i32x4 A00b = *(const i32x4*)(aRow0 + jb0 + hi8 + 4);
    i32x4 A01a = *(const i32x4*)(aRow0 + jb0 + 32 + hi8);
    i32x4 A01b = *(const i32x4*)(aRow0 + jb0 + 32 + hi8 + 4);
    i32x4 A10a = *(const i32x4*)(aRow1 + jb0 + hi8);
    i32x4 A10b = *(const i32x4*)(aRow1 + jb0 + hi8 + 4);
    i32x4 A11a = *(const i32x4*)(aRow1 + jb0 + 32 + hi8);
    i32x4 A11b = *(const i32x4*)(aRow1 + jb0 + 32 + hi8 + 4);
    __syncthreads();

    for (int s = 0; s < ns; ++s) {
        const int sel = s & 1;
        const int jb  = jb0 + (s << 6);
        const bool more = (s + 1 < ns);

        // (1) build P fragments for THIS step (frees the adj queue)
        float4 q0a = *(const float4*)&Wh2[jb + hi8];
        float4 q1a = *(const float4*)&Wh2[jb + hi8 + 4];
        float4 q0b = *(const float4*)&Wh2[jb + 32 + hi8];
        float4 q1b = *(const float4*)&Wh2[jb + 32 + hi8 + 4];
        f16x8 Bf00 = pcomp8(A00a, A00b, q0a, q1a, wh10, m0, s0);
        f16x8 Bf01 = pcomp8(A01a, A01b, q0b, q1b, wh10, m0, s0);
        f16x8 Bf10 = pcomp8(A10a, A10b, q0a, q1a, wh11, m1, s1);
        f16x8 Bf11 = pcomp8(A11a, A11b, q0b, q1b, wh11, m1, s1);

        // (2) issue WhT loads for step s+1 (regs; LDS write after MFMA)
        i32x4 wv0, wv1, wv2, wv3;
        if (more) {
            const f16* wsrc = WhT + jb + 64 + jc * 8;
            wv0 = *(const i32x4*)(wsrc + (size_t)(0 * 64 + sn) * NN);
            wv1 = *(const i32x4*)(wsrc + (size_t)(1 * 64 + sn) * NN);
            wv2 = *(const i32x4*)(wsrc + (size_t)(2 * 64 + sn) * NN);
            wv3 = *(const i32x4*)(wsrc + (size_t)(3 * 64 + sn) * NN);
        }

        // (3) refill adj queue for step s+1 (covered by MFMA + ds_write below)
        if (more) {
            const int jn = jb + 64;
            A00a = *(const i32x4*)(aRow0 + jn + hi8);
            A00b = *(const i32x4*)(aRow0 + jn + hi8 + 4);
            A01a = *(const i32x4*)(aRow0 + jn + 32 + hi8);
            A01b = *(const i32x4*)(aRow0 + jn + 32 + hi8 + 4);
            A10a = *(const i32x4*)(aRow1 + jn + hi8);
            A10b = *(const i32x4*)(aRow1 + jn + hi8 + 4);
            A11a = *(const i32x4*)(aRow1 + jn + 32 + hi8);
            A11b = *(const i32x4*)(aRow1 + jn + 32 + hi8 + 4);
        }

        // (4) MFMA: A = WhT from swizzled LDS, B = in-reg P
        const char* wb = (const char*)wbuf[sel];
        #pragma unroll
        for (int kt = 0; kt < 2; ++kt) {
            const int kb = (((kt * 4 + hi) << 4) ^ rx);
            f16x8 Af0 = *(const f16x8*)(wb + (nb +      r) * 128 + kb);
            f16x8 Af1 = *(const f16x8*)(wb + (nb + 16 + r) * 128 + kb);
            f16x8 Af2 = *(const f16x8*)(wb + (nb + 32 + r) * 128 + kb);
            f16x8 Af3 = *(const f16x8*)(wb + (nb + 48 + r) * 128 + kb);
            const f16x8 b0 = kt ? Bf01 : Bf00;
            const f16x8 b1 = kt ? Bf11 : Bf10;
            acc[0][0] = MFMA16(Af0, b0, acc[0][0]);
            acc[0][1] = MFMA16(Af1, b0, acc[0][1]);
            acc[0][2] = MFMA16(Af2, b0, acc[0][2]);
            acc[0][3] = MFMA16(Af3, b0, acc[0][3]);
            acc[1][0] = MFMA16(Af0, b1, acc[1][0]);
            acc[1][1] = MFMA16(Af1, b1, acc[1][1]);
            acc[1][2] = MFMA16(Af2, b1, acc[1][2]);
            acc[1][3] = MFMA16(Af3, b1, acc[1][3]);
        }

        // (5) write next WhT tile into the other buffer
        if (more) {
            char* wbn = (char*)wbuf[sel ^ 1];
            *(i32x4*)(wbn + (0 * 64 + sn) * 128 + swz) = wv0;
            *(i32x4*)(wbn + (1 * 64 + sn) * 128 + swz) = wv1;
            *(i32x4*)(wbn + (2 * 64 + sn) * 128 + swz) = wv2;
            *(i32x4*)(wbn + (3 * 64 + sn) * 128 + swz) = wv3;
        }
        __syncthreads();
    }

    // ---- row sums -> S (duplicated across nw waves; only nw==0 commits) ----
    s0 += __shfl_xor(s0, 16); s0 += __shfl_xor(s0, 32);
    s1 += __shfl_xor(s1, 16); s1 += __shfl_xor(s1, 32);
    if (nw == 0 && hi == 0) {
        atomicAdd(&S[ia], s0);
        atomicAdd(&S[ia + 16], s1);
    }

    // ---- partial D -> private slab js (D rows = n from MFMA; cols = i) ----
    // acc[ic][nc][q]: i = ia + ic*16, n = nb + nc*16 + hi*4 + q
    float* Dp = D + (size_t)js * NN * DD + (size_t)ia * DD + nb + hi * 4;
    #pragma unroll
    for (int ic = 0; ic < 2; ++ic)
        #pragma unroll
        for (int nc = 0; nc < 4; ++nc)
            __builtin_nontemporal_store(acc[ic][nc],
                (f32x4*)(Dp + (size_t)ic * 16 * DD + nc * 16));
}

// ---------------- K4: sum slabs + normalize + ELU ----------------
__global__ __launch_bounds__(256) void k4_finish(const float* __restrict__ D,
                                                 const float* __restrict__ S,
                                                 float* __restrict__ out,
                                                 int nslab) {
    const int g   = blockIdx.x * 256 + threadIdx.x;
    const int rw  = g >> 6;
    const int c4  = (g & 63) << 2;
    const size_t off = ((size_t)rw << 8) + c4;
    f32x4 v = {0.f, 0.f, 0.f, 0.f};
    for (int s = 0; s < nslab; ++s)
        v += __builtin_nontemporal_load((const f32x4*)&D[off + (size_t)s * NN * DD]);
    const float inv = 1.0f / S[rw];
    f32x4 o;
    #pragma unroll
    for (int q = 0; q < 4; ++q) {
        float x = v[q] * inv;
        o[q] = (x > 0.f) ? x : (__expf(x) - 1.f);
    }
    *(f32x4*)&out[off] = o;
}

extern "C" void kernel_launch(void* const* d_in, const int* in_sizes, int n_in,
                              void* d_out, int out_size, void* d_ws, size_t ws_size,
                              hipStream_t stream) {
    const float* h   = (const float*)d_in[0];
    const int*   adj = (const int*)d_in[1];
    const float* W   = (const float*)d_in[2];
    const float* a   = (const float*)d_in[3];
    float* out = (float*)d_out;

    char* ws = (char*)d_ws;
    f16*      WT     = (f16*)ws;                        // 128 KB
    f16*      WhT    = (f16*)(ws + 131072);             // 4 MB
    float*    r1     = (float*)(ws + 4325376);          // 1 KB
    float*    r2     = (float*)(ws + 4326400);          // 1 KB
    float*    Wh1    = (float*)(ws + 4327424);          // 32 KB
    float*    Wh2    = (float*)(ws + 4360192);          // 32 KB
    unsigned* maxkey = (unsigned*)(ws + 4392960);       // 4 B (pad 256)
    float*    S      = (float*)(ws + 4393216);          // 32 KB
    float*    D      = (float*)(ws + 4425984);          // js_n x 8 MB

    const size_t base = 4425984;
    const size_t slab = (size_t)NN * DD * 4;
    int js_n = 1, jshift = 0;
    if (ws_size >= base + 4 * slab)      { js_n = 4; jshift = 2; }
    else if (ws_size >= base + 2 * slab) { js_n = 2; jshift = 1; }
    const int jrange = NN / js_n;

    hipMemsetAsync(ws + 4392960, 0, 256 + 32768, stream);
    k0_prep<<<dim3(18), dim3(256), 0, stream>>>(W, a, WT, r1, r2);
    k1_gemm<<<dim3(512), dim3(256), 0, stream>>>(h, WT, r1, r2, WhT, Wh1, Wh2, maxkey);
    k3_attn<<<dim3(js_n * (NN / 64)), dim3(512), 0, stream>>>(adj, WhT, Wh1, Wh2, maxkey,
                                                              D, S, jrange, js_n - 1, jshift);
    k4_finish<<<dim3(2048), dim3(256), 0, stream>>>(D, S, out, js_n);
}

// Round 10
// 266.537 us; speedup vs baseline: 1.1887x; 1.1887x over previous
//
#include <hip/hip_runtime.h>

typedef _Float16 f16;
typedef _Float16 f16x4 __attribute__((ext_vector_type(4)));
typedef _Float16 f16x8 __attribute__((ext_vector_type(8)));
typedef float f32x4 __attribute__((ext_vector_type(4)));
typedef unsigned long long u64;

#define ALPHA 0.2f
#define NN 8192
#define DD 256
#define NW 256                  // NN/32 mask words per row
#define INVLN2 1.44269504088896f
#define MFMA16(a, b, c) __builtin_amdgcn_mfma_f32_16x16x32_f16(a, b, c, 0, 0, 0)

// ---------------- K0: prep — WT=f16(W^T), r1=W@a1*invln2, r2=W@a2*invln2 ----------
__global__ __launch_bounds__(256) void k0_prep(const float* __restrict__ W,
                                               const float* __restrict__ a,
                                               f16* __restrict__ WT,
                                               float* __restrict__ r1,
                                               float* __restrict__ r2) {
    const int b = blockIdx.x;
    const int t = threadIdx.x;
    if (b < 16) {
        __shared__ f16 tl[16][256];
        const int k0 = b * 16;
        const int kr = t >> 4, cb = (t & 15) << 4;
        #pragma unroll
        for (int p = 0; p < 4; ++p) {
            float4 v = *(const float4*)&W[(k0 + kr) * DD + cb + p * 4];
            tl[kr][cb + p * 4 + 0] = (f16)v.x;
            tl[kr][cb + p * 4 + 1] = (f16)v.y;
            tl[kr][cb + p * 4 + 2] = (f16)v.z;
            tl[kr][cb + p * 4 + 3] = (f16)v.w;
        }
        __syncthreads();
        f16 outv[16];
        #pragma unroll
        for (int q = 0; q < 16; ++q) outv[q] = tl[q][t];
        *(f16x8*)&WT[t * DD + k0]     = *(f16x8*)&outv[0];
        *(f16x8*)&WT[t * DD + k0 + 8] = *(f16x8*)&outv[8];
    } else {
        __shared__ float al[256];
        al[t] = a[(b - 16) * DD + t];
        __syncthreads();
        float s = 0.f;
        for (int k = 0; k < DD; ++k) s = fmaf(W[t * DD + k], al[k], s);
        float* rr = (b == 16) ? r1 : r2;
        rr[t] = s * INVLN2;
    }
}

// ---------------- K1: WhT = f16(h@W)^T via MFMA; wave0 also Wh1/Wh2 + maxkey ------
__global__ __launch_bounds__(256) void k1_gemm(const float* __restrict__ h,
                                               const f16* __restrict__ WT,
                                               const float* __restrict__ r1,
                                               const float* __restrict__ r2,
                                               f16* __restrict__ WhT,
                                               float* __restrict__ Wh1,
                                               float* __restrict__ Wh2,
                                               unsigned* __restrict__ maxkey) {
    const int t    = threadIdx.x;
    const int lane = t & 63;
    const int w    = t >> 6;
    const int i0   = blockIdx.x * 16;
    const int r    = lane & 15;
    const int hi   = lane >> 4;
    const int nbase = w * 64;

    f32x4 acc[4];
    #pragma unroll
    for (int nc = 0; nc < 4; ++nc) acc[nc] = (f32x4){0.f, 0.f, 0.f, 0.f};
    float s1 = 0.f, s2 = 0.f;

    const float* hrow = h + (size_t)(i0 + r) * DD;
    #pragma unroll
    for (int kt = 0; kt < 8; ++kt) {
        const int kb = kt * 32 + hi * 8;
        float4 h0 = *(const float4*)&hrow[kb];
        float4 h1 = *(const float4*)&hrow[kb + 4];
        f16x8 af;
        af[0] = (f16)h0.x; af[1] = (f16)h0.y; af[2] = (f16)h0.z; af[3] = (f16)h0.w;
        af[4] = (f16)h1.x; af[5] = (f16)h1.y; af[6] = (f16)h1.z; af[7] = (f16)h1.w;
        if (w == 0) {
            float4 ra0 = *(const float4*)&r1[kb];
            float4 ra1 = *(const float4*)&r1[kb + 4];
            float4 rb0 = *(const float4*)&r2[kb];
            float4 rb1 = *(const float4*)&r2[kb + 4];
            s1 += h0.x * ra0.x + h0.y * ra0.y + h0.z * ra0.z + h0.w * ra0.w
                + h1.x * ra1.x + h1.y * ra1.y + h1.z * ra1.z + h1.w * ra1.w;
            s2 += h0.x * rb0.x + h0.y * rb0.y + h0.z * rb0.z + h0.w * rb0.w
                + h1.x * rb1.x + h1.y * rb1.y + h1.z * rb1.z + h1.w * rb1.w;
        }
        #pragma unroll
        for (int nc = 0; nc < 4; ++nc) {
            f16x8 bf = *(const f16x8*)&WT[(nbase + nc * 16 + r) * DD + kb];
            acc[nc] = MFMA16(af, bf, acc[nc]);
        }
    }
    #pragma unroll
    for (int nc = 0; nc < 4; ++nc) {
        f16x4 o;
        o[0] = (f16)acc[nc][0]; o[1] = (f16)acc[nc][1];
        o[2] = (f16)acc[nc][2]; o[3] = (f16)acc[nc][3];
        *(f16x4*)&WhT[(size_t)(nbase + nc * 16 + r) * NN + i0 + hi * 4] = o;
    }
    if (w == 0) {
        s1 += __shfl_xor(s1, 16); s1 += __shfl_xor(s1, 32);
        s2 += __shfl_xor(s2, 16); s2 += __shfl_xor(s2, 32);
        if (lane < 16) {
            Wh1[i0 + lane] = s1;
            Wh2[i0 + lane] = s2;
            unsigned u = __float_as_uint(s2);
            u = (u & 0x80000000u) ? ~u : (u | 0x80000000u);
            atomicMax(maxkey, u);
        }
    }
}

// ---------------- K2: pack adj -> bitmask (one block per row, ballot) ----------------
__global__ __launch_bounds__(256) void k2_pack(const int* __restrict__ adj,
                                               unsigned* __restrict__ maskw) {
    const int row  = blockIdx.x;
    const int lane = threadIdx.x & 63;
    const int wv   = threadIdx.x >> 6;
    const int* arow = adj + (size_t)row * NN;
    unsigned* mrow  = maskw + (size_t)row * NW;
    for (int it = 0; it < 32; ++it) {
        const int j0 = (it * 4 + wv) * 64;
        int v = arow[j0 + lane];
        u64 m = __ballot(v > 0);
        if (lane == 0) mrow[j0 >> 5]       = (unsigned)m;
        if (lane == 1) mrow[(j0 >> 5) + 1] = (unsigned)(m >> 32);
    }
}

// ---------------- K3: barrier-free fused masked softmax + PV ----------------
// grid 512 x 256 thr (4 waves = 2iw x 2nw). js = bid&3 (XCD-window), itile = bid>>2.
// Block: 64 i-rows, n=256; wave tile 32i x 128n; j-steps of 64 over jrange=2048.
// NO LDS, NO barriers in the loop. A = WhT f16x8 from L2 (consume-then-reload per
// kt); B = P in-register (mask bits + Wh2 + exp2); mask u64 prefetched 1 step.
__device__ __forceinline__ f16x8 pcomp8(unsigned bits, float4 q0, float4 q1,
                                        float wh1r, float m_r, float& sacc) {
    float p[8];
    float e;
    e = wh1r + q0.x; e = fmaxf(e, ALPHA * e); p[0] = (bits & 1u)   ? exp2f(e - m_r) : 0.f;
    e = wh1r + q0.y; e = fmaxf(e, ALPHA * e); p[1] = (bits & 2u)   ? exp2f(e - m_r) : 0.f;
    e = wh1r + q0.z; e = fmaxf(e, ALPHA * e); p[2] = (bits & 4u)   ? exp2f(e - m_r) : 0.f;
    e = wh1r + q0.w; e = fmaxf(e, ALPHA * e); p[3] = (bits & 8u)   ? exp2f(e - m_r) : 0.f;
    e = wh1r + q1.x; e = fmaxf(e, ALPHA * e); p[4] = (bits & 16u)  ? exp2f(e - m_r) : 0.f;
    e = wh1r + q1.y; e = fmaxf(e, ALPHA * e); p[5] = (bits & 32u)  ? exp2f(e - m_r) : 0.f;
    e = wh1r + q1.z; e = fmaxf(e, ALPHA * e); p[6] = (bits & 64u)  ? exp2f(e - m_r) : 0.f;
    e = wh1r + q1.w; e = fmaxf(e, ALPHA * e); p[7] = (bits & 128u) ? exp2f(e - m_r) : 0.f;
    sacc += ((p[0] + p[1]) + (p[2] + p[3])) + ((p[4] + p[5]) + (p[6] + p[7]));
    f16x8 pk;
    pk[0] = (f16)p[0]; pk[1] = (f16)p[1]; pk[2] = (f16)p[2]; pk[3] = (f16)p[3];
    pk[4] = (f16)p[4]; pk[5] = (f16)p[5]; pk[6] = (f16)p[6]; pk[7] = (f16)p[7];
    return pk;
}

__global__ __launch_bounds__(256, 2) void k3_attn(const unsigned* __restrict__ maskw,
                                                  const f16* __restrict__ WhT,
                                                  const float* __restrict__ Wh1,
                                                  const float* __restrict__ Wh2,
                                                  const unsigned* __restrict__ maxkey,
                                                  float* __restrict__ D,
                                                  float* __restrict__ S,
                                                  int jrange, int jsmask, int jshift) {
    const int t     = threadIdx.x;
    const int lane  = t & 63;
    const int w     = t >> 6;
    const int js    = blockIdx.x & jsmask;
    const int itile = blockIdx.x >> jshift;
    const int i0    = itile * 64;
    const int jb0   = js * jrange;
    const int ns    = jrange >> 6;

    unsigned mk = *maxkey;
    const float maxW2 = __uint_as_float((mk & 0x80000000u) ? (mk & 0x7fffffffu) : ~mk);

    const int r   = lane & 15;
    const int hi  = lane >> 4;
    const int hi8 = hi << 3;
    const int iw  = w >> 1;          // i-half
    const int nw  = w & 1;           // n-half
    const int nb  = nw * 128;

    const int ia = i0 + iw * 32 + r;
    const float wh10 = Wh1[ia];
    const float wh11 = Wh1[ia + 16];
    float t0 = wh10 + maxW2, t1 = wh11 + maxW2;
    const float m0 = fmaxf(t0, ALPHA * t0);
    const float m1 = fmaxf(t1, ALPHA * t1);

    const unsigned* mrow0 = maskw + (size_t)ia * NW;
    const unsigned* mrow1 = mrow0 + 16 * NW;
    const f16* wbase = WhT + (size_t)(nb + r) * NN + jb0 + hi8;

    f32x4 acc[2][8];
    #pragma unroll
    for (int ic = 0; ic < 2; ++ic)
        #pragma unroll
        for (int nc = 0; nc < 8; ++nc) acc[ic][nc] = (f32x4){0.f, 0.f, 0.f, 0.f};
    float s0 = 0.f, s1 = 0.f;

    // prologue: A for (s=0,kt=0); mask for step 0
    f16x8 A[8];
    #pragma unroll
    for (int nc = 0; nc < 8; ++nc)
        A[nc] = *(const f16x8*)(wbase + (size_t)(nc * 16) * NN);
    u64 mb0 = *(const u64*)(mrow0 + (jb0 >> 5));
    u64 mb1 = *(const u64*)(mrow1 + (jb0 >> 5));

    for (int s = 0; s < ns; ++s) {
        const int jb = jb0 + (s << 6);
        const bool more = (s + 1 < ns);

        // prefetch mask for step s+1 (L2-resident window)
        u64 nm0 = 0, nm1 = 0;
        if (more) {
            nm0 = *(const u64*)(mrow0 + ((jb + 64) >> 5));
            nm1 = *(const u64*)(mrow1 + ((jb + 64) >> 5));
        }
        // Wh2 slices for both kt (L1-resident, 32KB table)
        float4 q00 = *(const float4*)&Wh2[jb + hi8];
        float4 q01 = *(const float4*)&Wh2[jb + hi8 + 4];
        float4 q10 = *(const float4*)&Wh2[jb + 32 + hi8];
        float4 q11 = *(const float4*)&Wh2[jb + 32 + hi8 + 4];

        // ---- kt = 0: P (VALU covers A-load latency), MFMA, reload A for kt=1 ----
        f16x8 B00 = pcomp8((unsigned)(mb0 >> hi8), q00, q01, wh10, m0, s0);
        f16x8 B01 = pcomp8((unsigned)(mb1 >> hi8), q00, q01, wh11, m1, s1);
        #pragma unroll
        for (int nc = 0; nc < 8; ++nc) {
            acc[0][nc] = MFMA16(A[nc], B00, acc[0][nc]);
            acc[1][nc] = MFMA16(A[nc], B01, acc[1][nc]);
        }
        #pragma unroll
        for (int nc = 0; nc < 8; ++nc)
            A[nc] = *(const f16x8*)(wbase + (size_t)(nc * 16) * NN + (s << 6) + 32);

        // ---- kt = 1 ----
        f16x8 B10 = pcomp8((unsigned)(mb0 >> (32 + hi8)), q10, q11, wh10, m0, s0);
        f16x8 B11 = pcomp8((unsigned)(mb1 >> (32 + hi8)), q10, q11, wh11, m1, s1);
        #pragma unroll
        for (int nc = 0; nc < 8; ++nc) {
            acc[0][nc] = MFMA16(A[nc], B10, acc[0][nc]);
            acc[1][nc] = MFMA16(A[nc], B11, acc[1][nc]);
        }
        if (more) {
            #pragma unroll
            for (int nc = 0; nc < 8; ++nc)
                A[nc] = *(const f16x8*)(wbase + (size_t)(nc * 16) * NN + (s << 6) + 64);
        }
        mb0 = nm0; mb1 = nm1;
    }

    // ---- row sums -> S (nw-duplicated; commit nw==0 only) ----
    s0 += __shfl_xor(s0, 16); s0 += __shfl_xor(s0, 32);
    s1 += __shfl_xor(s1, 16); s1 += __shfl_xor(s1, 32);
    if (nw == 0 && hi == 0) {
        atomicAdd(&S[ia], s0);
        atomicAdd(&S[ia + 16], s1);
    }

    // ---- partial D -> private slab js (verified mapping: n = nb+nc*16+hi*4+q) ----
    float* Dp = D + (size_t)js * NN * DD + (size_t)ia * DD + nb + hi * 4;
    #pragma unroll
    for (int ic = 0; ic < 2; ++ic)
        #pragma unroll
        for (int nc = 0; nc < 8; ++nc)
            __builtin_nontemporal_store(acc[ic][nc],
                (f32x4*)(Dp + (size_t)ic * 16 * DD + nc * 16));
}

// ---------------- K4: sum slabs + normalize + ELU ----------------
__global__ __launch_bounds__(256) void k4_finish(const float* __restrict__ D,
                                                 const float* __restrict__ S,
                                                 float* __restrict__ out,
                                                 int nslab) {
    const int g   = blockIdx.x * 256 + threadIdx.x;
    const int rw  = g >> 6;
    const int c4  = (g & 63) << 2;
    const size_t off = ((size_t)rw << 8) + c4;
    f32x4 v = {0.f, 0.f, 0.f, 0.f};
    for (int s = 0; s < nslab; ++s)
        v += __builtin_nontemporal_load((const f32x4*)&D[off + (size_t)s * NN * DD]);
    const float inv = 1.0f / S[rw];
    f32x4 o;
    #pragma unroll
    for (int q = 0; q < 4; ++q) {
        float x = v[q] * inv;
        o[q] = (x > 0.f) ? x : (__expf(x) - 1.f);
    }
    *(f32x4*)&out[off] = o;
}

extern "C" void kernel_launch(void* const* d_in, const int* in_sizes, int n_in,
                              void* d_out, int out_size, void* d_ws, size_t ws_size,
                              hipStream_t stream) {
    const float* h   = (const float*)d_in[0];
    const int*   adj = (const int*)d_in[1];
    const float* W   = (const float*)d_in[2];
    const float* a   = (const float*)d_in[3];
    float* out = (float*)d_out;

    char* ws = (char*)d_ws;
    f16*      WT     = (f16*)ws;                        // 128 KB
    f16*      WhT    = (f16*)(ws + 131072);             // 4 MB
    float*    r1     = (float*)(ws + 4325376);          // 1 KB
    float*    r2     = (float*)(ws + 4326400);          // 1 KB
    float*    Wh1    = (float*)(ws + 4327424);          // 32 KB
    float*    Wh2    = (float*)(ws + 4360192);          // 32 KB
    unsigned* maxkey = (unsigned*)(ws + 4392960);       // 4 B (pad 256)
    float*    S      = (float*)(ws + 4393216);          // 32 KB
    unsigned* maskw  = (unsigned*)(ws + 4425984);       // 8 MB bitmask
    float*    D      = (float*)(ws + 12814592);         // js_n x 8 MB

    const size_t base = 12814592;
    const size_t slab = (size_t)NN * DD * 4;
    int js_n = 1, jshift = 0;
    if (ws_size >= base + 4 * slab)      { js_n = 4; jshift = 2; }
    else if (ws_size >= base + 2 * slab) { js_n = 2; jshift = 1; }
    const int jrange = NN / js_n;

    hipMemsetAsync(ws + 4392960, 0, 256 + 32768, stream);
    k0_prep<<<dim3(18), dim3(256), 0, stream>>>(W, a, WT, r1, r2);
    k1_gemm<<<dim3(512), dim3(256), 0, stream>>>(h, WT, r1, r2, WhT, Wh1, Wh2, maxkey);
    k2_pack<<<dim3(8192), dim3(256), 0, stream>>>(adj, maskw);
    k3_attn<<<dim3(js_n * 128), dim3(256), 0, stream>>>(maskw, WhT, Wh1, Wh2, maxkey,
                                                        D, S, jrange, js_n - 1, jshift);
    k4_finish<<<dim3(2048), dim3(256), 0, stream>>>(D, S, out, js_n);
}